// Round 8
// baseline (196.757 us; speedup 1.0000x reference)
//
#include <hip/hip_runtime.h>
#include <hip/hip_fp16.h>

// EfficientAttention  B=4, S=4096, D=1024, fp32 in/out.
//   G[b] = x[b]^T x[b] (split-K=4, fp16 partials in d_out); Gh=(1/32)sum
//   Ph = Wv Gh ; KVt = Ph Wk^T + rank-1 bias ; Rt = KVt Wq^T ; E = x Rt^T + cv
// Big GEMMs: 256x256, 8 waves (2Mx4N), BK=64, 2 K-tiles/iter, 8 phases/iter.
// Reads (4/8 per phase) are issued ONE PHASE AHEAD of their MFMA; one
// half-block staged per phase; counted vmcnt(6) at phases 4 and 8 only.

#define BATCH 4
#define SEQ   4096
#define DM    1024

typedef _Float16 h8 __attribute__((ext_vector_type(8)));
typedef _Float16 h4 __attribute__((ext_vector_type(4)));
typedef float    f4 __attribute__((ext_vector_type(4)));

__device__ inline void gload_lds16(const _Float16* g, _Float16* l) {
    __builtin_amdgcn_global_load_lds(
        (const __attribute__((address_space(1))) void*)g,
        (__attribute__((address_space(3))) void*)l,
        16, 0, 0);
}

__device__ inline int xcd_swz(int bid, int grid) {
    const int q = grid >> 3;
    return (bid & 7) * q + (bid >> 3);
}

template<bool WRITE_RM>
__global__ __launch_bounds__(256) void cvt_transpose(
    const float* __restrict__ src, _Float16* __restrict__ dstT,
    _Float16* __restrict__ dstRM, int R, int C)
{
    __shared__ float tile[64][65];
    const long zoff = (long)blockIdx.z * R * C;
    src += zoff; dstT += zoff;
    if (WRITE_RM) dstRM += zoff;
    const int r0 = blockIdx.y * 64;
    const int c0 = blockIdx.x * 64;
    const int t  = threadIdx.x;
    const int tr = t >> 4;
    const int tc = (t & 15) * 4;
    #pragma unroll
    for (int i = 0; i < 4; ++i) {
        const int r = tr + i * 16;
        f4 v = *(const f4*)&src[(long)(r0 + r) * C + c0 + tc];
        tile[r][tc + 0] = v.x; tile[r][tc + 1] = v.y;
        tile[r][tc + 2] = v.z; tile[r][tc + 3] = v.w;
        if (WRITE_RM) {
            h4 h = { (_Float16)v.x, (_Float16)v.y, (_Float16)v.z, (_Float16)v.w };
            *(h4*)&dstRM[(long)(r0 + r) * C + c0 + tc] = h;
        }
    }
    __syncthreads();
    #pragma unroll
    for (int i = 0; i < 4; ++i) {
        const int c = tr + i * 16;
        h4 h = { (_Float16)tile[tc + 0][c], (_Float16)tile[tc + 1][c],
                 (_Float16)tile[tc + 2][c], (_Float16)tile[tc + 3][c] };
        *(h4*)&dstT[(long)(c0 + c) * R + r0 + tc] = h;
    }
}

__global__ __launch_bounds__(256) void cvt_pair(
    const float* __restrict__ s0, _Float16* __restrict__ d0,
    const float* __restrict__ s1, _Float16* __restrict__ d1)
{
    const int half = blockIdx.x >> 10;
    const long i = ((long)(blockIdx.x & 1023) * 256 + threadIdx.x) * 4;
    const float* s = half ? s1 : s0;
    _Float16*    d = half ? d1 : d0;
    f4 v = *(const f4*)(s + i);
    h4 h = { (_Float16)v.x, (_Float16)v.y, (_Float16)v.z, (_Float16)v.w };
    *(h4*)(d + i) = h;
}

__global__ __launch_bounds__(256) void rowsum_xt(
    const _Float16* __restrict__ xt, float* __restrict__ xs)
{
    const int gw   = blockIdx.x * 4 + (threadIdx.x >> 6);
    const int lane = threadIdx.x & 63;
    const _Float16* row = xt + (long)gw * SEQ;
    float s = 0.f;
    #pragma unroll
    for (int i = 0; i < SEQ; i += 512) {
        h8 v = *(const h8*)&row[i + lane * 8];
        #pragma unroll
        for (int j = 0; j < 8; ++j) s += (float)v[j];
    }
    #pragma unroll
    for (int off = 32; off; off >>= 1) s += __shfl_down(s, off);
    if (lane == 0) xs[gw] = s;
}

__global__ __launch_bounds__(256) void gemv_dual(
    const _Float16* __restrict__ Wvh, const _Float16* __restrict__ Wkh,
    const float* __restrict__ xs, const float* __restrict__ bv,
    float* __restrict__ dst)
{
    const int gw   = blockIdx.x * 4 + (threadIdx.x >> 6);
    const int half = gw >> 12;
    const int g    = gw & 4095;
    const int b    = g >> 10;
    const int o    = g & 1023;
    const int lane = threadIdx.x & 63;
    const _Float16* wr = (half ? Wkh : Wvh) + (long)o * 1024;
    const float*    v  = xs + b * 1024;
    float s = 0.f;
    #pragma unroll
    for (int i = 0; i < 2; ++i) {
        const int k = i * 512 + lane * 8;
        h8 wv = *(const h8*)&wr[k];
        f4 v0 = *(const f4*)&v[k];
        f4 v1 = *(const f4*)&v[k + 4];
        s += (float)wv[0] * v0.x + (float)wv[1] * v0.y +
             (float)wv[2] * v0.z + (float)wv[3] * v0.w +
             (float)wv[4] * v1.x + (float)wv[5] * v1.y +
             (float)wv[6] * v1.z + (float)wv[7] * v1.w;
    }
    #pragma unroll
    for (int off = 32; off; off >>= 1) s += __shfl_down(s, off);
    if (lane == 0) dst[gw] = s + (half ? 0.f : (float)SEQ * bv[o]);
}

__global__ __launch_bounds__(256) void gemv_k1024(
    const _Float16* __restrict__ W, long wZ,
    const float* __restrict__ vec, float* __restrict__ out)
{
    const int gw   = blockIdx.x * 4 + (threadIdx.x >> 6);
    const int b    = gw >> 10;
    const int o    = gw & 1023;
    const int lane = threadIdx.x & 63;
    const _Float16* wr = W + b * wZ + (long)o * 1024;
    float s = 0.f;
    #pragma unroll
    for (int i = 0; i < 2; ++i) {
        const int k = i * 512 + lane * 8;
        h8 wv = *(const h8*)&wr[k];
        f4 v0 = *(const f4*)&vec[k];
        f4 v1 = *(const f4*)&vec[k + 4];
        s += (float)wv[0] * v0.x + (float)wv[1] * v0.y +
             (float)wv[2] * v0.z + (float)wv[3] * v0.w +
             (float)wv[4] * v1.x + (float)wv[5] * v1.y +
             (float)wv[6] * v1.z + (float)wv[7] * v1.w;
    }
    #pragma unroll
    for (int off = 32; off; off >>= 1) s += __shfl_down(s, off);
    if (lane == 0) out[gw] = s;
}

__global__ __launch_bounds__(256) void reduce_gh(
    const _Float16* __restrict__ parts, _Float16* __restrict__ Gh)
{
    const long DD_ = (long)DM * DM;
    const long i = ((long)blockIdx.x * 256 + threadIdx.x) * 8;
    const long b = i >> 20;
    const long r = i & (DD_ - 1);
    const _Float16* p = parts + b * 4 * DD_ + r;
    h8 v0 = *(const h8*)&p[0];
    h8 v1 = *(const h8*)&p[DD_];
    h8 v2 = *(const h8*)&p[2 * DD_];
    h8 v3 = *(const h8*)&p[3 * DD_];
    h8 o;
    #pragma unroll
    for (int j = 0; j < 8; ++j) {
        float s = (float)v0[j] + (float)v1[j] + (float)v2[j] + (float)v3[j];
        o[j] = (_Float16)(s * 0.03125f);
    }
    *(h8*)&Gh[i] = o;
}

// ---------------------------------------------------------------------------
// 8-phase 256x256 NT GEMM, 2 K-tiles per iteration, read-ahead frag pipeline.
// Regions per buffer: [A0|A1|B0|B1] x 8192 halfs (16KB). buf0=even tile.
// Phase p: { ds_reads for phase p+1 ; stage 1 HB ; barrier ; 16 MFMA
//            (counted lgkmcnt auto) ; barrier }   vmcnt(6) at P4/P8 only.
// ---------------------------------------------------------------------------
template<typename OutT, int BIAS>
__global__ __launch_bounds__(512, 1) void gemm8p(
    const _Float16* __restrict__ A, const _Float16* __restrict__ B,
    OutT* __restrict__ C,
    int K, int lda, int ldb, int ldc, int tilesX, int perZ,
    long aZ, long bZ, long cZ, int sk, long aK, long bK,
    const float* __restrict__ bc1, long bc1Z, float alpha)
{
    __shared__ _Float16 lds[2][4][8192];   // [buf][A0,A1,B0,B1][HB] = 128 KiB

    const int L  = xcd_swz(blockIdx.x, gridDim.x);
    const int z  = L / perZ;
    const int r0 = L - z * perZ;
    const int zb = z / sk;
    const int zk = z - zb * sk;
    A += (long)zb * aZ + (long)zk * aK;
    B += (long)zb * bZ + (long)zk * bK;
    C += (long)z * cZ;
    const float* pc1 = (BIAS == 1) ? bc1 + (long)zb * bc1Z : nullptr;

    const int tileM = (r0 / tilesX) * 256;
    const int tileN = (r0 % tilesX) * 256;
    const int tid   = threadIdx.x;
    const int lane  = tid & 63;
    const int wave  = tid >> 6;
    const int wr    = wave >> 2;          // M half
    const int wc    = wave & 3;           // N quarter
    const int la    = lane & 15;
    const int kg    = lane >> 4;
    const int NT    = K >> 6;             // even (K multiple of 128)

    auto stageA = [&](int buf, int mq, int kt) {
        _Float16* dst = &lds[buf][mq][0];
        const int k0 = kt * 64;
        #pragma unroll
        for (int i = 0; i < 2; ++i) {
            const int U = i * 512 + tid;
            const int R = U >> 3, s = U & 7;
            const int gr = tileM + (R >> 6) * 128 + mq * 64 + (R & 63);
            gload_lds16(&A[(long)gr * lda + k0 + ((s ^ (R & 7)) << 3)], dst + U * 8);
        }
    };
    auto stageB = [&](int buf, int nq, int kt) {
        _Float16* dst = &lds[buf][2 + nq][0];
        const int k0 = kt * 64;
        #pragma unroll
        for (int i = 0; i < 2; ++i) {
            const int U = i * 512 + tid;
            const int R = U >> 3, s = U & 7;
            const int gn = tileN + (R >> 5) * 64 + nq * 32 + (R & 31);
            gload_lds16(&B[(long)gn * ldb + k0 + ((s ^ (R & 7)) << 3)], dst + U * 8);
        }
    };

    f4 acc[8][4] = {};
    h8 aS0[4][2], aS1[4][2];   // A frag slots (rotate statically)
    h8 bS0[2][2], bS1[2][2];   // B frag slots

    auto readA = [&](h8 (*dst)[2], int buf, int mq) {
        const _Float16* Ab = &lds[buf][mq][0];
        #pragma unroll
        for (int mi = 0; mi < 4; ++mi)
            #pragma unroll
            for (int kk = 0; kk < 2; ++kk) {
                const int R = wr * 64 + mi * 16 + la;
                const int s = kk * 4 + kg;
                dst[mi][kk] = *(const h8*)&Ab[R * 64 + ((s ^ (R & 7)) << 3)];
            }
    };
    auto readB = [&](h8 (*dst)[2], int buf, int nq) {
        const _Float16* Bb = &lds[buf][2 + nq][0];
        #pragma unroll
        for (int ni = 0; ni < 2; ++ni)
            #pragma unroll
            for (int kk = 0; kk < 2; ++kk) {
                const int R = wc * 32 + ni * 16 + la;
                const int s = kk * 4 + kg;
                dst[ni][kk] = *(const h8*)&Bb[R * 64 + ((s ^ (R & 7)) << 3)];
            }
    };
    auto mfmaQ = [&](int mq, int nq, h8 (*Af)[2], h8 (*Bf)[2]) {
        __builtin_amdgcn_s_setprio(1);
        #pragma unroll
        for (int mi = 0; mi < 4; ++mi)
            #pragma unroll
            for (int ni = 0; ni < 2; ++ni)
                #pragma unroll
                for (int kk = 0; kk < 2; ++kk)
                    acc[mq * 4 + mi][nq * 2 + ni] =
                        __builtin_amdgcn_mfma_f32_16x16x32_f16(
                            Af[mi][kk], Bf[ni][kk],
                            acc[mq * 4 + mi][nq * 2 + ni], 0, 0, 0);
        __builtin_amdgcn_s_setprio(0);
    };

    // prologue: stage tiles 0 (buf0) and 1 (buf1); land tile0; pre-read Q00(t0)
    stageA(0, 0, 0); stageA(0, 1, 0); stageB(0, 0, 0); stageB(0, 1, 0);
    stageA(1, 0, 1); stageA(1, 1, 1); stageB(1, 0, 1); stageB(1, 1, 1);
    asm volatile("s_waitcnt vmcnt(8)" ::: "memory");
    __builtin_amdgcn_sched_barrier(0);
    __builtin_amdgcn_s_barrier();
    readA(aS0, 0, 0);                      // A0(t0)
    readB(bS0, 0, 0);                      // B0(t0)
    asm volatile("s_waitcnt lgkmcnt(0)" ::: "memory");
    __builtin_amdgcn_sched_barrier(0);
    __builtin_amdgcn_s_barrier();

    for (int i = 0; i < NT / 2; ++i) {
        const int t  = 2 * i;
        const int t2 = (t + 2 < NT) ? t + 2 : NT - 1;   // clamped stage tiles
        const int t3 = (t + 3 < NT) ? t + 3 : NT - 1;
        // P1: MFMA Q00(t)[aS0,bS0]; read B1(t)->bS1; stage A0(t2)
        readB(bS1, 0, 1);
        stageA(0, 0, t2);
        __builtin_amdgcn_s_barrier();
        mfmaQ(0, 0, aS0, bS0);
        __builtin_amdgcn_s_barrier();
        // P2: MFMA Q01(t)[aS0,bS1]; read A1(t)->aS1; stage B0(t2)
        readA(aS1, 0, 1);
        stageB(0, 0, t2);
        __builtin_amdgcn_s_barrier();
        mfmaQ(0, 1, aS0, bS1);
        __builtin_amdgcn_s_barrier();
        // P3: MFMA Q10(t)[aS1,bS0]; read A0(t+1)->aS0; stage B1(t2)
        readA(aS0, 1, 0);
        stageB(0, 1, t2);
        __builtin_amdgcn_s_barrier();
        mfmaQ(1, 0, aS1, bS0);
        __builtin_amdgcn_s_barrier();
        // P4: MFMA Q11(t)[aS1,bS1]; read B0(t+1)->bS0; stage A1(t2); vmcnt(6)
        readB(bS0, 1, 0);
        stageA(0, 1, t2);
        __builtin_amdgcn_s_barrier();
        mfmaQ(1, 1, aS1, bS1);
        asm volatile("s_waitcnt vmcnt(6)" ::: "memory");
        __builtin_amdgcn_sched_barrier(0);
        __builtin_amdgcn_s_barrier();
        // P5: MFMA Q00(t+1)[aS0,bS0]; read B1(t+1)->bS1; stage A0(t3)
        readB(bS1, 1, 1);
        stageA(1, 0, t3);
        __builtin_amdgcn_s_barrier();
        mfmaQ(0, 0, aS0, bS0);
        __builtin_amdgcn_s_barrier();
        // P6: MFMA Q01(t+1)[aS0,bS1]; read A1(t+1)->aS1; stage B0(t3)
        readA(aS1, 1, 1);
        stageB(1, 0, t3);
        __builtin_amdgcn_s_barrier();
        mfmaQ(0, 1, aS0, bS1);
        __builtin_amdgcn_s_barrier();
        // P7: MFMA Q10(t+1)[aS1,bS0]; read A0(t+2)->aS0 (buf0); stage B1(t3)
        readA(aS0, 0, 0);
        stageB(1, 1, t3);
        __builtin_amdgcn_s_barrier();
        mfmaQ(1, 0, aS1, bS0);
        __builtin_amdgcn_s_barrier();
        // P8: MFMA Q11(t+1)[aS1,bS1]; read B0(t+2)->bS0 (buf0); stage A1(t3); vmcnt(6)
        readB(bS0, 0, 0);
        stageA(1, 1, t3);
        __builtin_amdgcn_s_barrier();
        mfmaQ(1, 1, aS1, bS1);
        asm volatile("s_waitcnt vmcnt(6)" ::: "memory");
        __builtin_amdgcn_sched_barrier(0);
        __builtin_amdgcn_s_barrier();
    }

    #pragma unroll
    for (int mf = 0; mf < 8; ++mf) {
        #pragma unroll
        for (int nf = 0; nf < 4; ++nf) {
            const int col = tileN + wc * 64 + nf * 16 + la;
            #pragma unroll
            for (int jj = 0; jj < 4; ++jj) {
                const int row = tileM + wr * 128 + mf * 16 + kg * 4 + jj;
                float v = acc[mf][nf][jj] * alpha;
                if (BIAS == 1) v += pc1[col];
                C[(long)row * ldc + col] = (OutT)v;
            }
        }
    }
}

// 64x64 NT GEMM for the 1024^3 chain.
template<int BIAS>
__global__ __launch_bounds__(256) void gemm64(
    const _Float16* __restrict__ A, const _Float16* __restrict__ B,
    _Float16* __restrict__ C,
    int K, int lda, int ldb, int ldc, int tilesX, int perZ,
    long aZ, long bZ, long cZ,
    const float* __restrict__ bc1, long bc1Z,
    const float* __restrict__ br1, long br1Z,
    const float* __restrict__ bc2, long bc2Z,
    const float* __restrict__ br2, long br2Z,
    float beta)
{
    __shared__ _Float16 As[64 * 64];
    __shared__ _Float16 Bs[64 * 64];

    const int L  = xcd_swz(blockIdx.x, gridDim.x);
    const int z  = L / perZ;
    const int r0 = L - z * perZ;
    A += (long)z * aZ;
    B += (long)z * bZ;
    C += (long)z * cZ;
    const float* pc1 = nullptr; const float* pr1 = nullptr;
    const float* pc2 = nullptr; const float* pr2 = nullptr;
    if (BIAS == 3) {
        pc1 = bc1 + (long)z * bc1Z; pr1 = br1 + (long)z * br1Z;
        pc2 = bc2 + (long)z * bc2Z; pr2 = br2 + (long)z * br2Z;
    }

    const int tileM = (r0 / tilesX) * 64;
    const int tileN = (r0 % tilesX) * 64;
    const int tid   = threadIdx.x;
    const int lane  = tid & 63;
    const int wave  = tid >> 6;
    const int wm    = (wave >> 1) * 32;
    const int wn    = (wave & 1) * 32;
    const int srow  = tid >> 3;
    const int sslot = tid & 7;

    f4 acc[2][2] = {};
    const int arow = lane & 15;
    const int kg   = lane >> 4;

    for (int k0 = 0; k0 < K; k0 += 64) {
        #pragma unroll
        for (int i = 0; i < 2; ++i) {
            const int row   = i * 32 + srow;
            const int gslot = sslot ^ (row & 7);
            gload_lds16(&A[(long)(tileM + row) * lda + k0 + gslot * 8],
                        &As[row * 64 + sslot * 8]);
            gload_lds16(&B[(long)(tileN + row) * ldb + k0 + gslot * 8],
                        &Bs[row * 64 + sslot * 8]);
        }
        __syncthreads();

        #pragma unroll
        for (int kk = 0; kk < 64; kk += 32) {
            h8 af[2], bf[2];
            #pragma unroll
            for (int m = 0; m < 2; ++m) {
                const int rr   = wm + m * 16 + arow;
                const int slot = (kk >> 3) + kg;
                af[m] = *(const h8*)&As[rr * 64 + ((slot ^ (rr & 7)) << 3)];
            }
            #pragma unroll
            for (int n = 0; n < 2; ++n) {
                const int rr   = wn + n * 16 + arow;
                const int slot = (kk >> 3) + kg;
                bf[n] = *(const h8*)&Bs[rr * 64 + ((slot ^ (rr & 7)) << 3)];
            }
            #pragma unroll
            for (int m = 0; m < 2; ++m)
                #pragma unroll
                for (int n = 0; n < 2; ++n)
                    acc[m][n] = __builtin_amdgcn_mfma_f32_16x16x32_f16(
                        af[m], bf[n], acc[m][n], 0, 0, 0);
        }
        __syncthreads();
    }

    #pragma unroll
    for (int m = 0; m < 2; ++m) {
        #pragma unroll
        for (int n = 0; n < 2; ++n) {
            const int col = tileN + wn + n * 16 + arow;
            #pragma unroll
            for (int j = 0; j < 4; ++j) {
                const int row = tileM + wm + m * 16 + (lane >> 4) * 4 + j;
                float v = acc[m][n][j];
                if (BIAS == 3) v += beta * (pc1[col] * pr1[row] + pc2[col] * pr2[row]);
                C[(long)row * ldc + col] = (_Float16)v;
            }
        }
    }
}

extern "C" void kernel_launch(void* const* d_in, const int* in_sizes, int n_in,
                              void* d_out, int out_size, void* d_ws, size_t ws_size,
                              hipStream_t stream)
{
    const float* x  = (const float*)d_in[0];
    const float* Wq = (const float*)d_in[1];
    const float* bq = (const float*)d_in[2];
    const float* Wk = (const float*)d_in[3];
    const float* bk = (const float*)d_in[4];
    const float* Wv = (const float*)d_in[5];
    const float* bv = (const float*)d_in[6];
    float* out = (float*)d_out;

    const long DD = (long)DM * DM;
    const long DS = (long)DM * SEQ;

    char* base = (char*)d_ws;
    _Float16* xh   = (_Float16*)base;
    _Float16* xt   = (_Float16*)(base + 32l * 1024 * 1024);
    _Float16* Gh   = xt;
    _Float16* Ph   = xt + 4l * 1024 * 1024;
    _Float16* KVth = xt + 8l * 1024 * 1024;
    _Float16* Rth  = xt + 12l * 1024 * 1024;
    _Float16* Wqt  = (_Float16*)(base + 64l * 1024 * 1024);
    _Float16* Wkh  = Wqt + DD;
    _Float16* Wvh  = Wkh + DD;
    float*    xs   = (float*)(Wvh + DD);
    float*    u2   = xs + 4 * 1024;
    float*    w    = u2 + 4 * 1024;
    float*    cv   = w + 4 * 1024;
    _Float16* parts = (_Float16*)d_out;   // [16][1024][1024] fp16 scratch

    cvt_transpose<true ><<<dim3(16, 64, 4), 256, 0, stream>>>(x,  xt,  xh, SEQ, DM);
    cvt_transpose<false><<<dim3(16, 16, 1), 256, 0, stream>>>(Wq, Wqt, nullptr, DM, DM);
    cvt_pair<<<2048, 256, 0, stream>>>(Wk, Wkh, Wv, Wvh);

    rowsum_xt<<<1024, 256, 0, stream>>>(xt, xs);
    gemv_dual<<<2048, 256, 0, stream>>>(Wvh, Wkh, xs, bv, u2);

    // Gram split-K=4: parts[b*4+k] = xt-slice @ xt-slice^T
    gemm8p<_Float16, 0><<<256, 512, 0, stream>>>(
        xt, xt, parts, 1024, SEQ, SEQ, DM, 4, 16,
        DS, DS, DD, 4, 1024, 1024, nullptr, 0, 1.0f);

    reduce_gh<<<2048, 256, 0, stream>>>(parts, Gh);

    gemm64<0><<<1024, 256, 0, stream>>>(
        Wvh, Gh, Ph, 1024, DM, DM, DM, 16, 256,
        0, DD, DD, nullptr, 0, nullptr, 0, nullptr, 0, nullptr, 0, 0.f);

    gemm64<3><<<1024, 256, 0, stream>>>(
        Ph, Wkh, KVth, 1024, DM, DM, DM, 16, 256,
        DD, 0, DD, bk, 0, u2, 1024, w, 1024, bv, 0, 0.03125f);

    gemv_k1024<<<1024, 256, 0, stream>>>(KVth, DD, bq, cv);

    gemm64<0><<<1024, 256, 0, stream>>>(
        KVth, Wqt, Rth, 1024, DM, DM, DM, 16, 256,
        DD, 0, DD, nullptr, 0, nullptr, 0, nullptr, 0, nullptr, 0, 0.f);

    // E = xh . Rth^T + cv -> fp32 out
    gemm8p<float, 1><<<256, 512, 0, stream>>>(
        xh, Rth, out, 1024, DM, DM, DM, 4, 64,
        DS, DD, DS, 1, 0, 0, cv, 1024, 1.0f);
}

// Round 10
// 168.055 us; speedup vs baseline: 1.1708x; 1.1708x over previous
//
#include <hip/hip_runtime.h>
#include <hip/hip_fp16.h>

// EfficientAttention  B=4, S=4096, D=1024, fp32 in/out.
//   G[b] = x^T x (split-K=4, fp16 partials in d_out); Gh = (1/32) sum parts
//   Ph[b] = Wv Gh[b]  (contains the 1/32!);  M = Wq^T Wk (batch-indep)
//   Rt[b] = Ph M^T + (1/32)(u2 ox qk + bv ox qw[b])
//   cv[b] = Ph kb + (1/32)(s1 u2 + s2[b] bv)
//   E[b]  = x Rt^T + cv
// Big GEMMs: R7-proven 8-phase 256x256 (T2..T5) + explicit lgkmcnt pin.

#define BATCH 4
#define SEQ   4096
#define DM    1024

typedef _Float16 h8 __attribute__((ext_vector_type(8)));
typedef _Float16 h4 __attribute__((ext_vector_type(4)));
typedef float    f4 __attribute__((ext_vector_type(4)));

__device__ inline void gload_lds16(const _Float16* g, _Float16* l) {
    __builtin_amdgcn_global_load_lds(
        (const __attribute__((address_space(1))) void*)g,
        (__attribute__((address_space(3))) void*)l,
        16, 0, 0);
}

__device__ inline int xcd_swz(int bid, int grid) {
    const int q = grid >> 3;
    return (bid & 7) * q + (bid >> 3);
}

// wave dot: fp16 row (1024) . f32 vec (1024)
__device__ inline float doth(const _Float16* wr, const float* v, int lane) {
    float s = 0.f;
    #pragma unroll
    for (int i = 0; i < 2; ++i) {
        const int k = i * 512 + lane * 8;
        h8 wv = *(const h8*)&wr[k];
        f4 v0 = *(const f4*)&v[k];
        f4 v1 = *(const f4*)&v[k + 4];
        s += (float)wv[0] * v0.x + (float)wv[1] * v0.y +
             (float)wv[2] * v0.z + (float)wv[3] * v0.w +
             (float)wv[4] * v1.x + (float)wv[5] * v1.y +
             (float)wv[6] * v1.z + (float)wv[7] * v1.w;
    }
    return s;
}
// wave dot: f32 . f32 (1024)
__device__ inline float dotf(const float* a, const float* b, int lane) {
    float s = 0.f;
    #pragma unroll
    for (int i = 0; i < 4; ++i) {
        const int k = i * 256 + lane * 4;
        f4 x = *(const f4*)&a[k];
        f4 y = *(const f4*)&b[k];
        s += x.x * y.x + x.y * y.y + x.z * y.z + x.w * y.w;
    }
    return s;
}
__device__ inline float wred(float s) {
    #pragma unroll
    for (int off = 32; off; off >>= 1) s += __shfl_down(s, off);
    return s;
}

// fp32 [Z][R][C] -> fp16 transposed [Z][C][R] + row-major fp16 (x only)
__global__ __launch_bounds__(256) void cvt_x(
    const float* __restrict__ src, _Float16* __restrict__ dstT,
    _Float16* __restrict__ dstRM, int R, int C)
{
    __shared__ float tile[64][65];
    const long zoff = (long)blockIdx.z * R * C;
    src += zoff; dstT += zoff; dstRM += zoff;
    const int r0 = blockIdx.y * 64;
    const int c0 = blockIdx.x * 64;
    const int t  = threadIdx.x;
    const int tr = t >> 4;
    const int tc = (t & 15) * 4;
    #pragma unroll
    for (int i = 0; i < 4; ++i) {
        const int r = tr + i * 16;
        f4 v = *(const f4*)&src[(long)(r0 + r) * C + c0 + tc];
        tile[r][tc + 0] = v.x; tile[r][tc + 1] = v.y;
        tile[r][tc + 2] = v.z; tile[r][tc + 3] = v.w;
        h4 h = { (_Float16)v.x, (_Float16)v.y, (_Float16)v.z, (_Float16)v.w };
        *(h4*)&dstRM[(long)(r0 + r) * C + c0 + tc] = h;
    }
    __syncthreads();
    #pragma unroll
    for (int i = 0; i < 4; ++i) {
        const int c = tr + i * 16;
        h4 h = { (_Float16)tile[tc + 0][c], (_Float16)tile[tc + 1][c],
                 (_Float16)tile[tc + 2][c], (_Float16)tile[tc + 3][c] };
        *(h4*)&dstT[(long)(c0 + c) * R + r0 + tc] = h;
    }
}

// weights: z=0 Wq->Wqt(T); z=1 Wk->Wkt(T)+Wkh(RM); z=2 Wv->Wvh(RM)
__global__ __launch_bounds__(256) void wcvt(
    const float* __restrict__ Wq, const float* __restrict__ Wk,
    const float* __restrict__ Wv,
    _Float16* __restrict__ Wqt, _Float16* __restrict__ Wkt,
    _Float16* __restrict__ Wkh, _Float16* __restrict__ Wvh)
{
    __shared__ float tile[64][65];
    const int z = blockIdx.z;
    const float* src = z == 0 ? Wq : (z == 1 ? Wk : Wv);
    _Float16* dstT  = z == 0 ? Wqt : (z == 1 ? Wkt : nullptr);
    _Float16* dstRM = z == 0 ? nullptr : (z == 1 ? Wkh : Wvh);
    const int r0 = blockIdx.y * 64;
    const int c0 = blockIdx.x * 64;
    const int t  = threadIdx.x;
    const int tr = t >> 4;
    const int tc = (t & 15) * 4;
    #pragma unroll
    for (int i = 0; i < 4; ++i) {
        const int r = tr + i * 16;
        f4 v = *(const f4*)&src[(long)(r0 + r) * DM + c0 + tc];
        tile[r][tc + 0] = v.x; tile[r][tc + 1] = v.y;
        tile[r][tc + 2] = v.z; tile[r][tc + 3] = v.w;
        if (dstRM) {
            h4 h = { (_Float16)v.x, (_Float16)v.y, (_Float16)v.z, (_Float16)v.w };
            *(h4*)&dstRM[(long)(r0 + r) * DM + c0 + tc] = h;
        }
    }
    __syncthreads();
    if (dstT) {
        #pragma unroll
        for (int i = 0; i < 4; ++i) {
            const int c = tr + i * 16;
            h4 h = { (_Float16)tile[tc + 0][c], (_Float16)tile[tc + 1][c],
                     (_Float16)tile[tc + 2][c], (_Float16)tile[tc + 3][c] };
            *(h4*)&dstT[(long)(c0 + c) * DM + r0 + tc] = h;
        }
    }
}

// xs[b*DM + d] = sum_s xt[b][d][s]
__global__ __launch_bounds__(256) void rowsum_xt(
    const _Float16* __restrict__ xt, float* __restrict__ xs)
{
    const int gw   = blockIdx.x * 4 + (threadIdx.x >> 6);
    const int lane = threadIdx.x & 63;
    const _Float16* row = xt + (long)gw * SEQ;
    float s = 0.f;
    #pragma unroll
    for (int i = 0; i < SEQ; i += 512) {
        h8 v = *(const h8*)&row[i + lane * 8];
        #pragma unroll
        for (int j = 0; j < 8; ++j) s += (float)v[j];
    }
    s = wred(s);
    if (lane == 0) xs[gw] = s;
}

// vecs = [u2 4096 | w 4096 | qk 1024 | kb 1024]
__global__ __launch_bounds__(256) void gemv_misc(
    const _Float16* __restrict__ Wvh, const _Float16* __restrict__ Wkh,
    const _Float16* __restrict__ Wqt, const _Float16* __restrict__ Wkt,
    const float* __restrict__ xs, const float* __restrict__ bv,
    const float* __restrict__ bk, const float* __restrict__ bq,
    float* __restrict__ vecs)
{
    const int gw   = blockIdx.x * 4 + (threadIdx.x >> 6);
    const int lane = threadIdx.x & 63;
    const _Float16* wr;
    const float* v;
    if (gw < 4096)      { wr = Wvh + (long)(gw & 1023) * DM; v = xs + (gw >> 10) * DM; }
    else if (gw < 8192) { wr = Wkh + (long)(gw & 1023) * DM; v = xs + ((gw - 4096) >> 10) * DM; }
    else if (gw < 9216) { wr = Wqt + (long)(gw - 8192) * DM; v = bk; }
    else                { wr = Wkt + (long)(gw - 9216) * DM; v = bq; }
    float s = wred(doth(wr, v, lane));
    if (lane == 0) {
        if (gw < 4096) s += (float)SEQ * bv[gw & 1023];
        vecs[gw] = s;
    }
}

// qw[b][i] = Wqt[i].w[b]; sv[0] = bq.bk; sv[1+b] = bq.w[b]
__global__ __launch_bounds__(256) void gemv_qw(
    const _Float16* __restrict__ Wqt, const float* __restrict__ w,
    const float* __restrict__ bq, const float* __restrict__ bk,
    float* __restrict__ qw, float* __restrict__ sv)
{
    const int gw   = blockIdx.x * 4 + (threadIdx.x >> 6);
    const int lane = threadIdx.x & 63;
    if (gw < 4096) {
        float s = wred(doth(Wqt + (long)(gw & 1023) * DM, w + (gw >> 10) * DM, lane));
        if (lane == 0) qw[gw] = s;
    } else if (gw == 4096) {
        float s = wred(dotf(bq, bk, lane));
        if (lane == 0) sv[0] = s;
    } else if (gw <= 4100) {
        float s = wred(dotf(bq, w + (gw - 4097) * DM, lane));
        if (lane == 0) sv[1 + (gw - 4097)] = s;
    }
}

// cv[b][e] = Ph[b][e].kb + (sv[0]*u2[b,e] + sv[1+b]*bv[e]) / 32
// (Ph already contains the 1/32 from Gh — do NOT rescale it)
__global__ __launch_bounds__(256) void gemv_cv(
    const _Float16* __restrict__ Ph, const float* __restrict__ kb,
    const float* __restrict__ u2, const float* __restrict__ bv,
    const float* __restrict__ sv, float* __restrict__ cv)
{
    const int gw   = blockIdx.x * 4 + (threadIdx.x >> 6);
    const int lane = threadIdx.x & 63;
    const int b    = gw >> 10;
    const int e    = gw & 1023;
    float s = wred(doth(Ph + (long)b * DM * DM + (long)e * DM, kb, lane));
    if (lane == 0)
        cv[gw] = s + (sv[0] * u2[gw] + sv[1 + b] * bv[e]) * 0.03125f;
}

// Gh = (1/32) * sum_{k<4} parts (fp16 partials)
__global__ __launch_bounds__(256) void reduce_gh(
    const _Float16* __restrict__ parts, _Float16* __restrict__ Gh)
{
    const long DD_ = (long)DM * DM;
    const long i = ((long)blockIdx.x * 256 + threadIdx.x) * 8;
    const long b = i >> 20;
    const long r = i & (DD_ - 1);
    const _Float16* p = parts + b * 4 * DD_ + r;
    h8 v0 = *(const h8*)&p[0];
    h8 v1 = *(const h8*)&p[DD_];
    h8 v2 = *(const h8*)&p[2 * DD_];
    h8 v3 = *(const h8*)&p[3 * DD_];
    h8 o;
    #pragma unroll
    for (int j = 0; j < 8; ++j) {
        float s = (float)v0[j] + (float)v1[j] + (float)v2[j] + (float)v3[j];
        o[j] = (_Float16)(s * 0.03125f);
    }
    *(h8*)&Gh[i] = o;
}

// ---------------------------------------------------------------------------
// 8-phase 256x256 NT GEMM (R7-proven schedule + explicit lgkm pin).
// ---------------------------------------------------------------------------
template<typename OutT, int BIAS>
__global__ __launch_bounds__(512, 1) void gemm8p(
    const _Float16* __restrict__ A, const _Float16* __restrict__ B,
    OutT* __restrict__ C,
    int K, int lda, int ldb, int ldc, int tilesX, int perZ,
    long aZ, long bZ, long cZ, int sk, long aK, long bK,
    const float* __restrict__ bc1, long bc1Z, float alpha)
{
    __shared__ _Float16 lds[2 * 32768];   // 128 KiB

    const int L  = xcd_swz(blockIdx.x, gridDim.x);
    const int z  = L / perZ;
    const int r0 = L - z * perZ;
    const int zb = z / sk;
    const int zk = z - zb * sk;
    A += (long)zb * aZ + (long)zk * aK;
    B += (long)zb * bZ + (long)zk * bK;
    C += (long)z * cZ;
    const float* pc1 = (BIAS == 1) ? bc1 + (long)zb * bc1Z : nullptr;

    const int tileM = (r0 / tilesX) * 256;
    const int tileN = (r0 % tilesX) * 256;
    const int tid   = threadIdx.x;
    const int lane  = tid & 63;
    const int wave  = tid >> 6;
    const int wr    = wave >> 2;
    const int wc    = wave & 3;
    const int la    = lane & 15;
    const int kg    = lane >> 4;

    auto stageA = [&](int buf, int mq, int kt) {
        _Float16* dst = &lds[buf * 32768 + mq * 8192];
        const int k0 = kt * 64;
        #pragma unroll
        for (int i = 0; i < 2; ++i) {
            const int U = i * 512 + tid;
            const int R = U >> 3, s = U & 7;
            const int gr = tileM + (R >> 6) * 128 + mq * 64 + (R & 63);
            gload_lds16(&A[(long)gr * lda + k0 + ((s ^ (R & 7)) << 3)], dst + U * 8);
        }
    };
    auto stageB = [&](int buf, int nq, int kt) {
        _Float16* dst = &lds[buf * 32768 + 16384 + nq * 8192];
        const int k0 = kt * 64;
        #pragma unroll
        for (int i = 0; i < 2; ++i) {
            const int U = i * 512 + tid;
            const int R = U >> 3, s = U & 7;
            const int gn = tileN + (R >> 5) * 64 + nq * 32 + (R & 31);
            gload_lds16(&B[(long)gn * ldb + k0 + ((s ^ (R & 7)) << 3)], dst + U * 8);
        }
    };

    f4 acc[8][4] = {};
    h8 af[4][2];
    h8 bf[2][2][2];

    auto readA = [&](int buf, int mq) {
        const _Float16* Ab = &lds[buf * 32768 + mq * 8192];
        #pragma unroll
        for (int mi = 0; mi < 4; ++mi)
            #pragma unroll
            for (int kk = 0; kk < 2; ++kk) {
                const int R = wr * 64 + mi * 16 + la;
                const int s = kk * 4 + kg;
                af[mi][kk] = *(const h8*)&Ab[R * 64 + ((s ^ (R & 7)) << 3)];
            }
    };
    auto readB = [&](int buf, int nq) {
        const _Float16* Bb = &lds[buf * 32768 + 16384 + nq * 8192];
        #pragma unroll
        for (int ni = 0; ni < 2; ++ni)
            #pragma unroll
            for (int kk = 0; kk < 2; ++kk) {
                const int R = wc * 32 + ni * 16 + la;
                const int s = kk * 4 + kg;
                bf[nq][ni][kk] = *(const h8*)&Bb[R * 64 + ((s ^ (R & 7)) << 3)];
            }
    };
    auto mfmaQ = [&](int mq, int nq) {
        __builtin_amdgcn_s_setprio(1);
        #pragma unroll
        for (int mi = 0; mi < 4; ++mi)
            #pragma unroll
            for (int ni = 0; ni < 2; ++ni)
                #pragma unroll
                for (int kk = 0; kk < 2; ++kk)
                    acc[mq * 4 + mi][nq * 2 + ni] =
                        __builtin_amdgcn_mfma_f32_16x16x32_f16(
                            af[mi][kk], bf[nq][ni][kk],
                            acc[mq * 4 + mi][nq * 2 + ni], 0, 0, 0);
        __builtin_amdgcn_s_setprio(0);
    };

    const int NT = K >> 6;

    stageA(0, 0, 0); stageA(0, 1, 0); stageB(0, 0, 0); stageB(0, 1, 0);
    if (NT > 1) {
        stageA(1, 0, 1); stageB(1, 0, 1);
        asm volatile("s_waitcnt vmcnt(4)" ::: "memory");
    } else {
        asm volatile("s_waitcnt vmcnt(0)" ::: "memory");
    }
    __builtin_amdgcn_sched_barrier(0);
    __builtin_amdgcn_s_barrier();

    for (int j = 0; j < NT; ++j) {
        const int buf = j & 1;
        // P1: mq0 nq0  (12 reads)
        readA(buf, 0); readB(buf, 0);
        if (j + 1 < NT) stageA(buf ^ 1, 1, j + 1);
        asm volatile("s_waitcnt lgkmcnt(8)" ::: "memory");
        __builtin_amdgcn_s_barrier();
        asm volatile("s_waitcnt lgkmcnt(0)" ::: "memory");
        __builtin_amdgcn_sched_barrier(0);
        mfmaQ(0, 0);
        __builtin_amdgcn_s_barrier();
        // P2: mq0 nq1  (4 reads)
        readB(buf, 1);
        if (j + 1 < NT) stageB(buf ^ 1, 1, j + 1);
        __builtin_amdgcn_s_barrier();
        asm volatile("s_waitcnt lgkmcnt(0)" ::: "memory");
        __builtin_amdgcn_sched_barrier(0);
        mfmaQ(0, 1);
        __builtin_amdgcn_s_barrier();
        // P3: mq1 nq0  (8 reads)
        readA(buf, 1);
        if (j + 2 < NT) stageA(buf, 0, j + 2);
        __builtin_amdgcn_s_barrier();
        asm volatile("s_waitcnt lgkmcnt(0)" ::: "memory");
        __builtin_amdgcn_sched_barrier(0);
        mfmaQ(1, 0);
        __builtin_amdgcn_s_barrier();
        // P4: mq1 nq1  (0 reads) + boundary vmcnt
        if (j + 2 < NT) stageB(buf, 0, j + 2);
        __builtin_amdgcn_s_barrier();
        mfmaQ(1, 1);
        if (j + 2 < NT) {
            asm volatile("s_waitcnt vmcnt(4)" ::: "memory");
        } else if (j + 1 < NT) {
            asm volatile("s_waitcnt vmcnt(0)" ::: "memory");
        }
        __builtin_amdgcn_sched_barrier(0);
        __builtin_amdgcn_s_barrier();
    }

    #pragma unroll
    for (int mf = 0; mf < 8; ++mf) {
        #pragma unroll
        for (int nf = 0; nf < 4; ++nf) {
            const int col = tileN + wc * 64 + nf * 16 + la;
            #pragma unroll
            for (int jj = 0; jj < 4; ++jj) {
                const int row = tileM + wr * 128 + mf * 16 + kg * 4 + jj;
                float v = acc[mf][nf][jj] * alpha;
                if (BIAS == 1) v += pc1[col];
                C[(long)row * ldc + col] = (OutT)v;
            }
        }
    }
}

// 64x64 NT GEMM (chain). Dual pointer set: z >= zSplit uses (A2,B2,C2), z'=0.
// BIAS: 0 none; 3: v = acc*alpha + beta*(bc1[col]*br1[row] + bc2[col]*br2[row])
template<int BIAS>
__global__ __launch_bounds__(256) void gemm64(
    const _Float16* __restrict__ A, const _Float16* __restrict__ B,
    _Float16* __restrict__ C,
    const _Float16* __restrict__ A2, const _Float16* __restrict__ B2,
    _Float16* __restrict__ C2, int zSplit,
    int K, int lda, int ldb, int ldc, int tilesX, int perZ,
    long aZ, long bZ, long cZ,
    const float* __restrict__ bc1, long bc1Z,
    const float* __restrict__ br1, long br1Z,
    const float* __restrict__ bc2, long bc2Z,
    const float* __restrict__ br2, long br2Z,
    float alpha, float beta)
{
    __shared__ _Float16 As[64 * 64];
    __shared__ _Float16 Bs[64 * 64];

    const int L  = xcd_swz(blockIdx.x, gridDim.x);
    int z        = L / perZ;
    const int r0 = L - z * perZ;
    if (z >= zSplit) { A = A2; B = B2; C = C2; z = 0; }
    A += (long)z * aZ;
    B += (long)z * bZ;
    C += (long)z * cZ;
    const float* pc1 = nullptr; const float* pr1 = nullptr;
    const float* pc2 = nullptr; const float* pr2 = nullptr;
    if (BIAS == 3) {
        pc1 = bc1 + (long)z * bc1Z; pr1 = br1 + (long)z * br1Z;
        pc2 = bc2 + (long)z * bc2Z; pr2 = br2 + (long)z * br2Z;
    }

    const int tileM = (r0 / tilesX) * 64;
    const int tileN = (r0 % tilesX) * 64;
    const int tid   = threadIdx.x;
    const int lane  = tid & 63;
    const int wave  = tid >> 6;
    const int wm    = (wave >> 1) * 32;
    const int wn    = (wave & 1) * 32;
    const int srow  = tid >> 3;
    const int sslot = tid & 7;

    f4 acc[2][2] = {};
    const int arow = lane & 15;
    const int kg   = lane >> 4;

    for (int k0 = 0; k0 < K; k0 += 64) {
        #pragma unroll
        for (int i = 0; i < 2; ++i) {
            const int row   = i * 32 + srow;
            const int gslot = sslot ^ (row & 7);
            gload_lds16(&A[(long)(tileM + row) * lda + k0 + gslot * 8],
                        &As[row * 64 + sslot * 8]);
            gload_lds16(&B[(long)(tileN + row) * ldb + k0 + gslot * 8],
                        &Bs[row * 64 + sslot * 8]);
        }
        __syncthreads();

        #pragma unroll
        for (int kk = 0; kk < 64; kk += 32) {
            h8 af[2], bf[2];
            #pragma unroll
            for (int m = 0; m < 2; ++m) {
                const int rr   = wm + m * 16 + arow;
                const int slot = (kk >> 3) + kg;
                af[m] = *(const h8*)&As[rr * 64 + ((slot ^ (rr & 7)) << 3)];
            }
            #pragma unroll
            for (int n = 0; n < 2; ++n) {
                const int rr   = wn + n * 16 + arow;
                const int slot = (kk >> 3) + kg;
                bf[n] = *(const h8*)&Bs[rr * 64 + ((slot ^ (rr & 7)) << 3)];
            }
            #pragma unroll
            for (int m = 0; m < 2; ++m)
                #pragma unroll
                for (int n = 0; n < 2; ++n)
                    acc[m][n] = __builtin_amdgcn_mfma_f32_16x16x32_f16(
                        af[m], bf[n], acc[m][n], 0, 0, 0);
        }
        __syncthreads();
    }

    #pragma unroll
    for (int m = 0; m < 2; ++m) {
        #pragma unroll
        for (int n = 0; n < 2; ++n) {
            const int col = tileN + wn + n * 16 + arow;
            #pragma unroll
            for (int j = 0; j < 4; ++j) {
                const int row = tileM + wm + m * 16 + (lane >> 4) * 4 + j;
                float v = acc[m][n][j] * alpha;
                if (BIAS == 3) v += beta * (pc1[col] * pr1[row] + pc2[col] * pr2[row]);
                C[(long)row * ldc + col] = (_Float16)v;
            }
        }
    }
}

extern "C" void kernel_launch(void* const* d_in, const int* in_sizes, int n_in,
                              void* d_out, int out_size, void* d_ws, size_t ws_size,
                              hipStream_t stream)
{
    const float* x  = (const float*)d_in[0];
    const float* Wq = (const float*)d_in[1];
    const float* bq = (const float*)d_in[2];
    const float* Wk = (const float*)d_in[3];
    const float* bk = (const float*)d_in[4];
    const float* Wv = (const float*)d_in[5];
    const float* bv = (const float*)d_in[6];
    float* out = (float*)d_out;

    const long DD = (long)DM * DM;
    const long DS = (long)DM * SEQ;
    const long MB = 1024l * 1024;

    char* base = (char*)d_ws;
    _Float16* xh   = (_Float16*)base;
    _Float16* xt   = (_Float16*)(base + 32 * MB);
    _Float16* Gh   = xt;                                  // 8MB
    _Float16* Ph   = (_Float16*)(base + 40 * MB);         // 8MB
    _Float16* Rth  = (_Float16*)(base + 48 * MB);         // 8MB
    _Float16* Wqt  = (_Float16*)(base + 64 * MB);
    _Float16* Wkh  = (_Float16*)(base + 66 * MB);
    _Float16* Wvh  = (_Float16*)(base + 68 * MB);
    _Float16* Wkt  = (_Float16*)(base + 70 * MB);
    _Float16* Mh   = (_Float16*)(base + 72 * MB);
    float*    vecs = (float*)(base + 74 * MB);
    float*    u2   = vecs;                // 4096
    float*    w    = vecs + 4096;         // 4096
    float*    qk   = vecs + 8192;         // 1024
    float*    kb   = vecs + 9216;         // 1024
    float*    xs   = vecs + 10240;        // 4096
    float*    qw   = vecs + 14336;        // 4096
    float*    cv   = vecs + 18432;        // 4096
    float*    sv   = vecs + 22528;        // 8
    _Float16* parts = (_Float16*)d_out;   // 32MB fp16 scratch

    // 1) converts
    cvt_x<<<dim3(16, 64, 4), 256, 0, stream>>>(x, xt, xh, SEQ, DM);
    wcvt<<<dim3(16, 16, 3), 256, 0, stream>>>(Wq, Wk, Wv, Wqt, Wkt, Wkh, Wvh);

    // 2) xs = rowsum(xt)
    rowsum_xt<<<1024, 256, 0, stream>>>(xt, xs);

    // 3) u2, w, qk, kb
    gemv_misc<<<2560, 256, 0, stream>>>(Wvh, Wkh, Wqt, Wkt, xs, bv, bk, bq, vecs);

    // 4) qw, s1, s2
    gemv_qw<<<1026, 256, 0, stream>>>(Wqt, w, bq, bk, qw, sv);

    // 5) Gram split-K=4: parts[b*4+k] = xt-slice @ xt-slice^T
    gemm8p<_Float16, 0><<<256, 512, 0, stream>>>(
        xt, xt, parts, 1024, SEQ, SEQ, DM, 4, 16,
        DS, DS, DD, 4, 1024, 1024, nullptr, 0, 1.0f);

    // 6) Gh = (1/32)*sum parts
    reduce_gh<<<2048, 256, 0, stream>>>(parts, Gh);

    // 7) Ph[b] = Wv.Gh[b] (z<4)  ||  Mh = Wqt.Wkt^T-NT (z=4)
    gemm64<0><<<1280, 256, 0, stream>>>(
        Wvh, Gh, Ph, Wqt, Wkt, Mh, 4,
        1024, DM, DM, DM, 16, 256,
        0, DD, DD,
        nullptr, 0, nullptr, 0, nullptr, 0, nullptr, 0, 1.0f, 0.f);

    // 8) cv[b][e] = Ph.kb + (s1*u2 + s2*bv)/32
    gemv_cv<<<1024, 256, 0, stream>>>(Ph, kb, u2, bv, sv, cv);

    // 9) Rt[b] = Ph.M^T + (1/32)(qk ox u2 + qw ox bv)   [alpha=1: Ph has the 1/32]
    gemm64<3><<<1024, 256, 0, stream>>>(
        Ph, Mh, Rth, nullptr, nullptr, nullptr, 99,
        1024, DM, DM, DM, 16, 256,
        DD, 0, DD,
        qk, 0, u2, 1024, qw, 1024, bv, 0, 1.0f, 0.03125f);

    // 10) E[b] = xh.Rt^T + cv -> fp32 out
    gemm8p<float, 1><<<256, 512, 0, stream>>>(
        xh, Rth, out, 1024, DM, DM, DM, 4, 64,
        DS, DD, DS, 1, 0, 0, cv, 1024, 1.0f);
}

// Round 11
// 156.855 us; speedup vs baseline: 1.2544x; 1.0714x over previous
//
#include <hip/hip_runtime.h>
#include <hip/hip_fp16.h>

// EfficientAttention  B=4, S=4096, D=1024, fp32 in/out.
//   G[b] = x^T x  — SYMMETRIC: only lower-tri 256^2 tiles (10/batch), split-K=6
//          -> parts[job*6+s] (fp16, d_out scratch); Gh = (1/32) sum_s, mirrored.
//   Ph[b] = Wv Gh[b] (has the 1/32);  M = Wq^T Wk
//   Rt[b] = Ph M^T + (1/32)(u2 ox qk + bv ox qw[b]);  cv = Ph kb + (s1 u2 + s2 bv)/32
//   E[b]  = x Rt^T + cv
// Big GEMMs: 8-phase 256x256 (T2..T5, R7-proven schedule).

#define BATCH 4
#define SEQ   4096
#define DM    1024

typedef _Float16 h8 __attribute__((ext_vector_type(8)));
typedef _Float16 h4 __attribute__((ext_vector_type(4)));
typedef float    f4 __attribute__((ext_vector_type(4)));

__device__ inline void gload_lds16(const _Float16* g, _Float16* l) {
    __builtin_amdgcn_global_load_lds(
        (const __attribute__((address_space(1))) void*)g,
        (__attribute__((address_space(3))) void*)l,
        16, 0, 0);
}

__device__ inline int xcd_swz(int bid, int grid) {
    const int q = grid >> 3;
    return (bid & 7) * q + (bid >> 3);
}

__device__ inline float doth(const _Float16* wr, const float* v, int lane) {
    float s = 0.f;
    #pragma unroll
    for (int i = 0; i < 2; ++i) {
        const int k = i * 512 + lane * 8;
        h8 wv = *(const h8*)&wr[k];
        f4 v0 = *(const f4*)&v[k];
        f4 v1 = *(const f4*)&v[k + 4];
        s += (float)wv[0] * v0.x + (float)wv[1] * v0.y +
             (float)wv[2] * v0.z + (float)wv[3] * v0.w +
             (float)wv[4] * v1.x + (float)wv[5] * v1.y +
             (float)wv[6] * v1.z + (float)wv[7] * v1.w;
    }
    return s;
}
__device__ inline float dotf(const float* a, const float* b, int lane) {
    float s = 0.f;
    #pragma unroll
    for (int i = 0; i < 4; ++i) {
        const int k = i * 256 + lane * 4;
        f4 x = *(const f4*)&a[k];
        f4 y = *(const f4*)&b[k];
        s += x.x * y.x + x.y * y.y + x.z * y.z + x.w * y.w;
    }
    return s;
}
__device__ inline float wred(float s) {
    #pragma unroll
    for (int off = 32; off; off >>= 1) s += __shfl_down(s, off);
    return s;
}

// fp32 x [Z][S][D] -> xt [Z][D][S] fp16 + xh row-major fp16 + xs col-sums (atomic)
__global__ __launch_bounds__(256) void cvt_x(
    const float* __restrict__ src, _Float16* __restrict__ dstT,
    _Float16* __restrict__ dstRM, float* __restrict__ xs, int R, int C)
{
    __shared__ float tile[64][65];
    __shared__ float red[4][64];
    const long zoff = (long)blockIdx.z * R * C;
    src += zoff; dstT += zoff; dstRM += zoff;
    const int r0 = blockIdx.y * 64;
    const int c0 = blockIdx.x * 64;
    const int t  = threadIdx.x;
    const int tr = t >> 4;
    const int tc = (t & 15) * 4;
    #pragma unroll
    for (int i = 0; i < 4; ++i) {
        const int r = tr + i * 16;
        f4 v = *(const f4*)&src[(long)(r0 + r) * C + c0 + tc];
        tile[r][tc + 0] = v.x; tile[r][tc + 1] = v.y;
        tile[r][tc + 2] = v.z; tile[r][tc + 3] = v.w;
        h4 h = { (_Float16)v.x, (_Float16)v.y, (_Float16)v.z, (_Float16)v.w };
        *(h4*)&dstRM[(long)(r0 + r) * C + c0 + tc] = h;
    }
    __syncthreads();
    #pragma unroll
    for (int i = 0; i < 4; ++i) {
        const int c = tr + i * 16;
        h4 h = { (_Float16)tile[tc + 0][c], (_Float16)tile[tc + 1][c],
                 (_Float16)tile[tc + 2][c], (_Float16)tile[tc + 3][c] };
        *(h4*)&dstT[(long)(c0 + c) * R + r0 + tc] = h;
    }
    // column sums (over this tile's 64 s-rows) -> atomicAdd into xs[b][c0+c]
    {
        const int cc = t & 63;
        const int rb = (t >> 6) * 16;
        float ps = 0.f;
        #pragma unroll
        for (int r = 0; r < 16; ++r) ps += tile[rb + r][cc];
        red[t >> 6][cc] = ps;
    }
    __syncthreads();
    if (t < 64)
        atomicAdd(&xs[blockIdx.z * DM + c0 + t],
                  red[0][t] + red[1][t] + red[2][t] + red[3][t]);
}

// weights: z=0 Wq->Wqt(T); z=1 Wk->Wkt(T)+Wkh(RM); z=2 Wv->Wvh(RM)
__global__ __launch_bounds__(256) void wcvt(
    const float* __restrict__ Wq, const float* __restrict__ Wk,
    const float* __restrict__ Wv,
    _Float16* __restrict__ Wqt, _Float16* __restrict__ Wkt,
    _Float16* __restrict__ Wkh, _Float16* __restrict__ Wvh)
{
    __shared__ float tile[64][65];
    const int z = blockIdx.z;
    const float* src = z == 0 ? Wq : (z == 1 ? Wk : Wv);
    _Float16* dstT  = z == 0 ? Wqt : (z == 1 ? Wkt : nullptr);
    _Float16* dstRM = z == 0 ? nullptr : (z == 1 ? Wkh : Wvh);
    const int r0 = blockIdx.y * 64;
    const int c0 = blockIdx.x * 64;
    const int t  = threadIdx.x;
    const int tr = t >> 4;
    const int tc = (t & 15) * 4;
    #pragma unroll
    for (int i = 0; i < 4; ++i) {
        const int r = tr + i * 16;
        f4 v = *(const f4*)&src[(long)(r0 + r) * DM + c0 + tc];
        tile[r][tc + 0] = v.x; tile[r][tc + 1] = v.y;
        tile[r][tc + 2] = v.z; tile[r][tc + 3] = v.w;
        if (dstRM) {
            h4 h = { (_Float16)v.x, (_Float16)v.y, (_Float16)v.z, (_Float16)v.w };
            *(h4*)&dstRM[(long)(r0 + r) * DM + c0 + tc] = h;
        }
    }
    __syncthreads();
    if (dstT) {
        #pragma unroll
        for (int i = 0; i < 4; ++i) {
            const int c = tr + i * 16;
            h4 h = { (_Float16)tile[tc + 0][c], (_Float16)tile[tc + 1][c],
                     (_Float16)tile[tc + 2][c], (_Float16)tile[tc + 3][c] };
            *(h4*)&dstT[(long)(c0 + c) * DM + r0 + tc] = h;
        }
    }
}

// vecs = [u2 4096 | w 4096 | qk 1024 | kb 1024]
__global__ __launch_bounds__(256) void gemv_misc(
    const _Float16* __restrict__ Wvh, const _Float16* __restrict__ Wkh,
    const _Float16* __restrict__ Wqt, const _Float16* __restrict__ Wkt,
    const float* __restrict__ xs, const float* __restrict__ bv,
    const float* __restrict__ bk, const float* __restrict__ bq,
    float* __restrict__ vecs)
{
    const int gw   = blockIdx.x * 4 + (threadIdx.x >> 6);
    const int lane = threadIdx.x & 63;
    const _Float16* wr;
    const float* v;
    if (gw < 4096)      { wr = Wvh + (long)(gw & 1023) * DM; v = xs + (gw >> 10) * DM; }
    else if (gw < 8192) { wr = Wkh + (long)(gw & 1023) * DM; v = xs + ((gw - 4096) >> 10) * DM; }
    else if (gw < 9216) { wr = Wqt + (long)(gw - 8192) * DM; v = bk; }
    else                { wr = Wkt + (long)(gw - 9216) * DM; v = bq; }
    float s = wred(doth(wr, v, lane));
    if (lane == 0) {
        if (gw < 4096) s += (float)SEQ * bv[gw & 1023];
        vecs[gw] = s;
    }
}

// qw[b][i] = Wqt[i].w[b]; sv[0] = bq.bk; sv[1+b] = bq.w[b]
__global__ __launch_bounds__(256) void gemv_qw(
    const _Float16* __restrict__ Wqt, const float* __restrict__ w,
    const float* __restrict__ bq, const float* __restrict__ bk,
    float* __restrict__ qw, float* __restrict__ sv)
{
    const int gw   = blockIdx.x * 4 + (threadIdx.x >> 6);
    const int lane = threadIdx.x & 63;
    if (gw < 4096) {
        float s = wred(doth(Wqt + (long)(gw & 1023) * DM, w + (gw >> 10) * DM, lane));
        if (lane == 0) qw[gw] = s;
    } else if (gw == 4096) {
        float s = wred(dotf(bq, bk, lane));
        if (lane == 0) sv[0] = s;
    } else if (gw <= 4100) {
        float s = wred(dotf(bq, w + (gw - 4097) * DM, lane));
        if (lane == 0) sv[1 + (gw - 4097)] = s;
    }
}

// cv[b][e] = Ph[b][e].kb + (sv[0]*u2 + sv[1+b]*bv)/32
__global__ __launch_bounds__(256) void gemv_cv(
    const _Float16* __restrict__ Ph, const float* __restrict__ kb,
    const float* __restrict__ u2, const float* __restrict__ bv,
    const float* __restrict__ sv, float* __restrict__ cv)
{
    const int gw   = blockIdx.x * 4 + (threadIdx.x >> 6);
    const int lane = threadIdx.x & 63;
    const int b    = gw >> 10;
    const int e    = gw & 1023;
    float s = wred(doth(Ph + (long)b * DM * DM + (long)e * DM, kb, lane));
    if (lane == 0)
        cv[gw] = s + (sv[0] * u2[gw] + sv[1 + b] * bv[e]) * 0.03125f;
}

// Triangular reduce+mirror: Gh[b] from parts[job*6+s] (each 256x256 fp16).
// 640 blocks = 40 jobs x 16 (64x64 chunks). Mirror via LDS transpose.
__global__ __launch_bounds__(256) void reduce_tri(
    const _Float16* __restrict__ parts, _Float16* __restrict__ Gh)
{
    __shared__ _Float16 lds[64][72];
    const int bid = blockIdx.x;
    const int job = bid >> 4;
    const int ch  = bid & 15;
    const int b   = job / 10;
    const int p   = job - b * 10;
    const int ti  = p >= 6 ? 3 : (p >= 3 ? 2 : (p >= 1 ? 1 : 0));
    const int tj  = p - ((ti * (ti + 1)) >> 1);
    const int li  = (ch >> 2) * 64;
    const int lj  = (ch & 3) * 64;
    const int t   = threadIdx.x;
    const int c8  = (t & 7) * 8;
    const long DD_ = (long)DM * DM;

    h8 o[2];
    #pragma unroll
    for (int h = 0; h < 2; ++h) {
        const int r = (t >> 3) + h * 32;
        float a[8] = {};
        #pragma unroll
        for (int s = 0; s < 6; ++s) {
            const _Float16* src = parts + ((long)(job * 6 + s) << 16);
            h8 v = *(const h8*)&src[(li + r) * 256 + lj + c8];
            #pragma unroll
            for (int j = 0; j < 8; ++j) a[j] += (float)v[j];
        }
        #pragma unroll
        for (int j = 0; j < 8; ++j) o[h][j] = (_Float16)(a[j] * 0.03125f);
        // direct write
        *(h8*)&Gh[b * DD_ + (long)(ti * 256 + li + r) * DM + tj * 256 + lj + c8] = o[h];
        *(h8*)&lds[r][c8] = o[h];
    }
    if (ti != tj) {
        __syncthreads();
        #pragma unroll
        for (int h = 0; h < 2; ++h) {
            const int r = (t >> 3) + h * 32;   // row within mirror tile (lj side)
            h8 m;
            #pragma unroll
            for (int j = 0; j < 8; ++j) m[j] = lds[c8 + j][r];
            *(h8*)&Gh[b * DD_ + (long)(tj * 256 + lj + r) * DM + ti * 256 + li + c8] = m;
        }
    }
}

// ---------------------------------------------------------------------------
// 8-phase 256x256 NT GEMM (R7-proven schedule). TRI=1: triangular Gram mode.
// ---------------------------------------------------------------------------
template<typename OutT, int BIAS, int TRI>
__global__ __launch_bounds__(512, 1) void gemm8p(
    const _Float16* __restrict__ A, const _Float16* __restrict__ B,
    OutT* __restrict__ C,
    int K, int lda, int ldb, int ldc, int tilesX, int perZ,
    long aZ, long bZ, long cZ, int sk, long aK, long bK,
    const float* __restrict__ bc1, long bc1Z, float alpha)
{
    __shared__ _Float16 lds[2 * 32768];   // 128 KiB

    const int L = xcd_swz(blockIdx.x, gridDim.x);
    int tileM, tileN, cTileM, cTileN, NT;
    const float* pc1 = nullptr;
    if (TRI) {
        // L in [0,240): job = L/6 (b*10+p), s = L%6. K slices {704x4, 640x2}.
        const int job = L / 6;
        const int s   = L - job * 6;
        const int b   = job / 10;
        const int p   = job - b * 10;
        const int ti  = p >= 6 ? 3 : (p >= 3 ? 2 : (p >= 1 ? 1 : 0));
        const int tj  = p - ((ti * (ti + 1)) >> 1);
        const int kOff = s < 4 ? s * 704 : 2816 + (s - 4) * 640;
        NT = s < 4 ? 11 : 10;
        A += (long)b * aZ + kOff;
        B += (long)b * aZ + kOff;
        C += (long)(job * 6 + s) * cZ;
        tileM = ti * 256; tileN = tj * 256;
        cTileM = 0; cTileN = 0;
    } else {
        const int z  = L / perZ;
        const int r0 = L - z * perZ;
        const int zb = z / sk;
        const int zk = z - zb * sk;
        A += (long)zb * aZ + (long)zk * aK;
        B += (long)zb * bZ + (long)zk * bK;
        C += (long)z * cZ;
        if (BIAS == 1) pc1 = bc1 + (long)zb * bc1Z;
        tileM = (r0 / tilesX) * 256;
        tileN = (r0 % tilesX) * 256;
        cTileM = tileM; cTileN = tileN;
        NT = K >> 6;
    }

    const int tid  = threadIdx.x;
    const int lane = tid & 63;
    const int wave = tid >> 6;
    const int wr   = wave >> 2;
    const int wc   = wave & 3;
    const int la   = lane & 15;
    const int kg   = lane >> 4;

    auto stageA = [&](int buf, int mq, int kt) {
        _Float16* dst = &lds[buf * 32768 + mq * 8192];
        const int k0 = kt * 64;
        #pragma unroll
        for (int i = 0; i < 2; ++i) {
            const int U = i * 512 + tid;
            const int R = U >> 3, s = U & 7;
            const int gr = tileM + (R >> 6) * 128 + mq * 64 + (R & 63);
            gload_lds16(&A[(long)gr * lda + k0 + ((s ^ (R & 7)) << 3)], dst + U * 8);
        }
    };
    auto stageB = [&](int buf, int nq, int kt) {
        _Float16* dst = &lds[buf * 32768 + 16384 + nq * 8192];
        const int k0 = kt * 64;
        #pragma unroll
        for (int i = 0; i < 2; ++i) {
            const int U = i * 512 + tid;
            const int R = U >> 3, s = U & 7;
            const int gn = tileN + (R >> 5) * 64 + nq * 32 + (R & 31);
            gload_lds16(&B[(long)gn * ldb + k0 + ((s ^ (R & 7)) << 3)], dst + U * 8);
        }
    };

    f4 acc[8][4] = {};
    h8 af[4][2];
    h8 bf[2][2][2];

    auto readA = [&](int buf, int mq) {
        const _Float16* Ab = &lds[buf * 32768 + mq * 8192];
        #pragma unroll
        for (int mi = 0; mi < 4; ++mi)
            #pragma unroll
            for (int kk = 0; kk < 2; ++kk) {
                const int R = wr * 64 + mi * 16 + la;
                const int s = kk * 4 + kg;
                af[mi][kk] = *(const h8*)&Ab[R * 64 + ((s ^ (R & 7)) << 3)];
            }
    };
    auto readB = [&](int buf, int nq) {
        const _Float16* Bb = &lds[buf * 32768 + 16384 + nq * 8192];
        #pragma unroll
        for (int ni = 0; ni < 2; ++ni)
            #pragma unroll
            for (int kk = 0; kk < 2; ++kk) {
                const int R = wc * 32 + ni * 16 + la;
                const int s = kk * 4 + kg;
                bf[nq][ni][kk] = *(const h8*)&Bb[R * 64 + ((s ^ (R & 7)) << 3)];
            }
    };
    auto mfmaQ = [&](int mq, int nq) {
        __builtin_amdgcn_s_setprio(1);
        #pragma unroll
        for (int mi = 0; mi < 4; ++mi)
            #pragma unroll
            for (int ni = 0; ni < 2; ++ni)
                #pragma unroll
                for (int kk = 0; kk < 2; ++kk)
                    acc[mq * 4 + mi][nq * 2 + ni] =
                        __builtin_amdgcn_mfma_f32_16x16x32_f16(
                            af[mi][kk], bf[nq][ni][kk],
                            acc[mq * 4 + mi][nq * 2 + ni], 0, 0, 0);
        __builtin_amdgcn_s_setprio(0);
    };

    stageA(0, 0, 0); stageA(0, 1, 0); stageB(0, 0, 0); stageB(0, 1, 0);
    if (NT > 1) {
        stageA(1, 0, 1); stageB(1, 0, 1);
        asm volatile("s_waitcnt vmcnt(4)" ::: "memory");
    } else {
        asm volatile("s_waitcnt vmcnt(0)" ::: "memory");
    }
    __builtin_amdgcn_sched_barrier(0);
    __builtin_amdgcn_s_barrier();

    for (int j = 0; j < NT; ++j) {
        const int buf = j & 1;
        // P1
        readA(buf, 0); readB(buf, 0);
        if (j + 1 < NT) stageA(buf ^ 1, 1, j + 1);
        asm volatile("s_waitcnt lgkmcnt(8)" ::: "memory");
        __builtin_amdgcn_s_barrier();
        asm volatile("s_waitcnt lgkmcnt(0)" ::: "memory");
        __builtin_amdgcn_sched_barrier(0);
        mfmaQ(0, 0);
        __builtin_amdgcn_s_barrier();
        // P2
        readB(buf, 1);
        if (j + 1 < NT) stageB(buf ^ 1, 1, j + 1);
        __builtin_amdgcn_s_barrier();
        asm volatile("s_waitcnt lgkmcnt(0)" ::: "memory");
        __builtin_amdgcn_sched_barrier(0);
        mfmaQ(0, 1);
        __builtin_amdgcn_s_barrier();
        // P3
        readA(buf, 1);
        if (j + 2 < NT) stageA(buf, 0, j + 2);
        __builtin_amdgcn_s_barrier();
        asm volatile("s_waitcnt lgkmcnt(0)" ::: "memory");
        __builtin_amdgcn_sched_barrier(0);
        mfmaQ(1, 0);
        __builtin_amdgcn_s_barrier();
        // P4
        if (j + 2 < NT) stageB(buf, 0, j + 2);
        __builtin_amdgcn_s_barrier();
        mfmaQ(1, 1);
        if (j + 2 < NT) {
            asm volatile("s_waitcnt vmcnt(4)" ::: "memory");
        } else if (j + 1 < NT) {
            asm volatile("s_waitcnt vmcnt(0)" ::: "memory");
        }
        __builtin_amdgcn_sched_barrier(0);
        __builtin_amdgcn_s_barrier();
    }

    #pragma unroll
    for (int mf = 0; mf < 8; ++mf) {
        #pragma unroll
        for (int nf = 0; nf < 4; ++nf) {
            const int col = cTileN + wc * 64 + nf * 16 + la;
            #pragma unroll
            for (int jj = 0; jj < 4; ++jj) {
                const int row = cTileM + wr * 128 + mf * 16 + kg * 4 + jj;
                float v = acc[mf][nf][jj] * alpha;
                if (BIAS == 1) v += pc1[col];
                C[(long)row * ldc + col] = (OutT)v;
            }
        }
    }
}

// 64x64 NT GEMM (chain). z >= zSplit -> (A2,B2,C2), z'=0.
template<int BIAS>
__global__ __launch_bounds__(256) void gemm64(
    const _Float16* __restrict__ A, const _Float16* __restrict__ B,
    _Float16* __restrict__ C,
    const _Float16* __restrict__ A2, const _Float16* __restrict__ B2,
    _Float16* __restrict__ C2, int zSplit,
    int K, int lda, int ldb, int ldc, int tilesX, int perZ,
    long aZ, long bZ, long cZ,
    const float* __restrict__ bc1, long bc1Z,
    const float* __restrict__ br1, long br1Z,
    const float* __restrict__ bc2, long bc2Z,
    const float* __restrict__ br2, long br2Z,
    float alpha, float beta)
{
    __shared__ _Float16 As[64 * 64];
    __shared__ _Float16 Bs[64 * 64];

    const int L  = xcd_swz(blockIdx.x, gridDim.x);
    int z        = L / perZ;
    const int r0 = L - z * perZ;
    if (z >= zSplit) { A = A2; B = B2; C = C2; z = 0; }
    A += (long)z * aZ;
    B += (long)z * bZ;
    C += (long)z * cZ;
    const float* pc1 = nullptr; const float* pr1 = nullptr;
    const float* pc2 = nullptr; const float* pr2 = nullptr;
    if (BIAS == 3) {
        pc1 = bc1 + (long)z * bc1Z; pr1 = br1 + (long)z * br1Z;
        pc2 = bc2 + (long)z * bc2Z; pr2 = br2 + (long)z * br2Z;
    }

    const int tileM = (r0 / tilesX) * 64;
    const int tileN = (r0 % tilesX) * 64;
    const int tid   = threadIdx.x;
    const int lane  = tid & 63;
    const int wave  = tid >> 6;
    const int wm    = (wave >> 1) * 32;
    const int wn    = (wave & 1) * 32;
    const int srow  = tid >> 3;
    const int sslot = tid & 7;

    f4 acc[2][2] = {};
    const int arow = lane & 15;
    const int kg   = lane >> 4;

    for (int k0 = 0; k0 < K; k0 += 64) {
        #pragma unroll
        for (int i = 0; i < 2; ++i) {
            const int row   = i * 32 + srow;
            const int gslot = sslot ^ (row & 7);
            gload_lds16(&A[(long)(tileM + row) * lda + k0 + gslot * 8],
                        &As[row * 64 + sslot * 8]);
            gload_lds16(&B[(long)(tileN + row) * ldb + k0 + gslot * 8],
                        &Bs[row * 64 + sslot * 8]);
        }
        __syncthreads();

        #pragma unroll
        for (int kk = 0; kk < 64; kk += 32) {
            h8 af[2], bf[2];
            #pragma unroll
            for (int m = 0; m < 2; ++m) {
                const int rr   = wm + m * 16 + arow;
                const int slot = (kk >> 3) + kg;
                af[m] = *(const h8*)&As[rr * 64 + ((slot ^ (rr & 7)) << 3)];
            }
            #pragma unroll
            for (int n = 0; n < 2; ++n) {
                const int rr   = wn + n * 16 + arow;
                const int slot = (kk >> 3) + kg;
                bf[n] = *(const h8*)&Bs[rr * 64 + ((slot ^ (rr & 7)) << 3)];
            }
            #pragma unroll
            for (int m = 0; m < 2; ++m)
                #pragma unroll
                for (int n = 0; n < 2; ++n)
                    acc[m][n] = __builtin_amdgcn_mfma_f32_16x16x32_f16(
                        af[m], bf[n], acc[m][n], 0, 0, 0);
        }
        __syncthreads();
    }

    #pragma unroll
    for (int m = 0; m < 2; ++m) {
        #pragma unroll
        for (int n = 0; n < 2; ++n) {
            const int col = tileN + wn + n * 16 + arow;
            #pragma unroll
            for (int j = 0; j < 4; ++j) {
                const int row = tileM + wm + m * 16 + (lane >> 4) * 4 + j;
                float v = acc[m][n][j] * alpha;
                if (BIAS == 3) v += beta * (pc1[col] * pr1[row] + pc2[col] * pr2[row]);
                C[(long)row * ldc + col] = (_Float16)v;
            }
        }
    }
}

extern "C" void kernel_launch(void* const* d_in, const int* in_sizes, int n_in,
                              void* d_out, int out_size, void* d_ws, size_t ws_size,
                              hipStream_t stream)
{
    const float* x  = (const float*)d_in[0];
    const float* Wq = (const float*)d_in[1];
    const float* bq = (const float*)d_in[2];
    const float* Wk = (const float*)d_in[3];
    const float* bk = (const float*)d_in[4];
    const float* Wv = (const float*)d_in[5];
    const float* bv = (const float*)d_in[6];
    float* out = (float*)d_out;

    const long DD = (long)DM * DM;
    const long DS = (long)DM * SEQ;
    const long MB = 1024l * 1024;

    char* base = (char*)d_ws;
    _Float16* xh   = (_Float16*)base;
    _Float16* xt   = (_Float16*)(base + 32 * MB);
    _Float16* Gh   = xt;                                  // 8MB (after xt dead)
    _Float16* Ph   = (_Float16*)(base + 40 * MB);
    _Float16* Rth  = (_Float16*)(base + 48 * MB);
    _Float16* Wqt  = (_Float16*)(base + 64 * MB);
    _Float16* Wkh  = (_Float16*)(base + 66 * MB);
    _Float16* Wvh  = (_Float16*)(base + 68 * MB);
    _Float16* Wkt  = (_Float16*)(base + 70 * MB);
    _Float16* Mh   = (_Float16*)(base + 72 * MB);
    float*    vecs = (float*)(base + 74 * MB);
    float*    u2   = vecs;                // 4096
    float*    w    = vecs + 4096;         // 4096
    float*    qk   = vecs + 8192;         // 1024
    float*    kb   = vecs + 9216;         // 1024
    float*    xs   = vecs + 10240;        // 4096
    float*    qw   = vecs + 14336;        // 4096
    float*    cv   = vecs + 18432;        // 4096
    float*    sv   = vecs + 22528;        // 8
    _Float16* parts = (_Float16*)d_out;   // 240 x 256^2 fp16 = 30MB scratch

    // 0) zero xs (accumulated atomically by cvt_x)
    hipMemsetAsync(xs, 0, BATCH * DM * sizeof(float), stream);

    // 1) converts (+ fused col-sums into xs)
    cvt_x<<<dim3(16, 64, 4), 256, 0, stream>>>(x, xt, xh, xs, SEQ, DM);
    wcvt<<<dim3(16, 16, 3), 256, 0, stream>>>(Wq, Wk, Wv, Wqt, Wkt, Wkh, Wvh);

    // 2) u2, w, qk, kb
    gemv_misc<<<2560, 256, 0, stream>>>(Wvh, Wkh, Wqt, Wkt, xs, bv, bk, bq, vecs);

    // 3) qw, s1, s2
    gemv_qw<<<1026, 256, 0, stream>>>(Wqt, w, bq, bk, qw, sv);

    // 4) Triangular Gram: parts[job*6+s] = lower-tri 256^2 tile, K-slice s
    gemm8p<_Float16, 0, 1><<<240, 512, 0, stream>>>(
        xt, xt, parts, 4096, SEQ, SEQ, 256, 0, 0,
        DS, DS, 65536, 1, 0, 0, nullptr, 0, 1.0f);

    // 5) Gh = (1/32)*sum_s parts, mirrored to upper triangle
    reduce_tri<<<640, 256, 0, stream>>>(parts, Gh);

    // 6) Ph[b] = Wv.Gh[b] (z<4)  ||  Mh = Wqt.Wkt^T (z=4)
    gemm64<0><<<1280, 256, 0, stream>>>(
        Wvh, Gh, Ph, Wqt, Wkt, Mh, 4,
        1024, DM, DM, DM, 16, 256,
        0, DD, DD,
        nullptr, 0, nullptr, 0, nullptr, 0, nullptr, 0, 1.0f, 0.f);

    // 7) cv[b][e] = Ph.kb + (s1*u2 + s2*bv)/32
    gemv_cv<<<1024, 256, 0, stream>>>(Ph, kb, u2, bv, sv, cv);

    // 8) Rt[b] = Ph.M^T + (1/32)(qk ox u2 + qw ox bv)
    gemm64<3><<<1024, 256, 0, stream>>>(
        Ph, Mh, Rth, nullptr, nullptr, nullptr, 99,
        1024, DM, DM, DM, 16, 256,
        DD, 0, DD,
        qk, 0, u2, 1024, qw, 1024, bv, 0, 1.0f, 0.03125f);

    // 9) E[b] = xh.Rt^T + cv -> fp32 out
    gemm8p<float, 1, 0><<<256, 512, 0, stream>>>(
        xh, Rth, out, 1024, DM, DM, DM, 4, 64,
        DS, DD, DS, 1, 0, 0, cv, 1024, 1.0f);
}